// Round 1
// baseline (734.859 us; speedup 1.0000x reference)
//
#include <hip/hip_runtime.h>
#include <math.h>

// Problem constants
#define N_NODES 100000
#define N_EDGES 1600000
#define IN_DIM  128
#define HD      64     // HEADS * OUT_DIM
#define HEADS   4
#define ODIM    16
#define NEG_SLOPE 0.2f

// ---------------------------------------------------------------------------
// Kernel 1: h = feat @ W   (N x 128) @ (128 x 64) -> (N x 64)
// 64-node x 64-col tile per block, 256 threads, 4x4 register tile per thread.
// ---------------------------------------------------------------------------
__global__ __launch_bounds__(256) void k_gemm(const float* __restrict__ feat,
                                              const float* __restrict__ W,
                                              float* __restrict__ hws) {
    __shared__ float sF[64][IN_DIM + 1];  // [node][k], +1 pad breaks bank conflicts
    __shared__ float sW[IN_DIM][HD];      // [k][col]

    const int tid  = threadIdx.x;
    const int base = blockIdx.x * 64;

    // Load W tile (full W: 128x64)
    for (int i = tid; i < IN_DIM * HD; i += 256) {
        sW[i >> 6][i & 63] = W[i];
    }
    // Load feat tile: 64 nodes x 128
    for (int i = tid; i < 64 * IN_DIM; i += 256) {
        int n = i >> 7, k = i & 127;
        int gn = base + n;
        sF[n][k] = (gn < N_NODES) ? feat[gn * IN_DIM + k] : 0.f;
    }
    __syncthreads();

    const int cg = (tid & 15) * 4;   // col base (0..60)
    const int rg = (tid >> 4) * 4;   // local node base (0..60)

    float acc[4][4] = {};
    for (int k = 0; k < IN_DIM; ++k) {
        float4 wv = *(const float4*)&sW[k][cg];
        float f0 = sF[rg + 0][k];
        float f1 = sF[rg + 1][k];
        float f2 = sF[rg + 2][k];
        float f3 = sF[rg + 3][k];
        acc[0][0] += f0 * wv.x; acc[0][1] += f0 * wv.y; acc[0][2] += f0 * wv.z; acc[0][3] += f0 * wv.w;
        acc[1][0] += f1 * wv.x; acc[1][1] += f1 * wv.y; acc[1][2] += f1 * wv.z; acc[1][3] += f1 * wv.w;
        acc[2][0] += f2 * wv.x; acc[2][1] += f2 * wv.y; acc[2][2] += f2 * wv.z; acc[2][3] += f2 * wv.w;
        acc[3][0] += f3 * wv.x; acc[3][1] += f3 * wv.y; acc[3][2] += f3 * wv.z; acc[3][3] += f3 * wv.w;
    }

    for (int r = 0; r < 4; ++r) {
        int gn = base + rg + r;
        if (gn < N_NODES) {
            float4 v = make_float4(acc[r][0], acc[r][1], acc[r][2], acc[r][3]);
            *(float4*)&hws[gn * HD + cg] = v;
        }
    }
}

// ---------------------------------------------------------------------------
// Kernel 2: el[n][h] = sum_d h[n][h][d]*attn_l[h][d];  er likewise
// One thread per (node, head).
// ---------------------------------------------------------------------------
__global__ __launch_bounds__(256) void k_attn_halves(const float* __restrict__ hws,
                                                     const float* __restrict__ attn_l,
                                                     const float* __restrict__ attn_r,
                                                     float* __restrict__ el,
                                                     float* __restrict__ er) {
    int idx = blockIdx.x * 256 + threadIdx.x;
    if (idx >= N_NODES * HEADS) return;
    int n = idx >> 2, h = idx & 3;
    const float* hp = hws + n * HD + h * ODIM;
    const float* al = attn_l + h * ODIM;
    const float* ar = attn_r + h * ODIM;
    float sl = 0.f, sr = 0.f;
    #pragma unroll
    for (int d = 0; d < ODIM; ++d) {
        float v = hp[d];
        sl += v * al[d];
        sr += v * ar[d];
    }
    el[idx] = sl;
    er[idx] = sr;
}

// ---------------------------------------------------------------------------
// Kernel 3: init out = bias (broadcast), emax = -inf, denom = 0
// ---------------------------------------------------------------------------
__global__ __launch_bounds__(256) void k_init(float* __restrict__ out,
                                              const float* __restrict__ bias,
                                              float* __restrict__ emax,
                                              float* __restrict__ denom) {
    int idx = blockIdx.x * 256 + threadIdx.x;
    if (idx < N_NODES * HD) {
        out[idx] = bias[idx & 63];
    }
    if (idx < N_NODES * HEADS) {
        emax[idx]  = -INFINITY;
        denom[idx] = 0.f;
    }
}

__device__ inline void atomicMaxF(float* addr, float v) {
    if (v >= 0.f) {
        atomicMax((int*)addr, __float_as_int(v));
    } else {
        atomicMin((unsigned int*)addr, (unsigned int)__float_as_int(v));
    }
}

__device__ inline float leaky(float x) {
    return x > 0.f ? x : NEG_SLOPE * x;
}

// ---------------------------------------------------------------------------
// Kernel 4: segment max of per-edge logits. One thread per (edge, head).
// ---------------------------------------------------------------------------
__global__ __launch_bounds__(256) void k_edge_max(const int* __restrict__ src,
                                                  const int* __restrict__ dst,
                                                  const float* __restrict__ el,
                                                  const float* __restrict__ er,
                                                  float* __restrict__ emax) {
    int idx = blockIdx.x * 256 + threadIdx.x;
    if (idx >= N_EDGES * HEADS) return;
    int e = idx >> 2, h = idx & 3;
    int s = src[e], d = dst[e];
    float x = leaky(el[s * HEADS + h] + er[d * HEADS + h]);
    atomicMaxF(&emax[d * HEADS + h], x);
}

// ---------------------------------------------------------------------------
// Kernel 5: denom = segment_sum(exp(e - emax[dst]))
// ---------------------------------------------------------------------------
__global__ __launch_bounds__(256) void k_edge_expsum(const int* __restrict__ src,
                                                     const int* __restrict__ dst,
                                                     const float* __restrict__ el,
                                                     const float* __restrict__ er,
                                                     const float* __restrict__ emax,
                                                     float* __restrict__ denom) {
    int idx = blockIdx.x * 256 + threadIdx.x;
    if (idx >= N_EDGES * HEADS) return;
    int e = idx >> 2, h = idx & 3;
    int s = src[e], d = dst[e];
    int dh = d * HEADS + h;
    float x  = leaky(el[s * HEADS + h] + er[dh]);
    float ex = __expf(x - emax[dh]);
    atomicAdd(&denom[dh], ex);
}

// ---------------------------------------------------------------------------
// Kernel 6: out[dst] += h[src] * alpha    (alpha recomputed from el/er/emax/denom)
// One thread per (edge, out-col). 64 threads (one wave) per edge.
// ---------------------------------------------------------------------------
__global__ __launch_bounds__(256) void k_aggregate(const int* __restrict__ src,
                                                   const int* __restrict__ dst,
                                                   const float* __restrict__ hws,
                                                   const float* __restrict__ el,
                                                   const float* __restrict__ er,
                                                   const float* __restrict__ emax,
                                                   const float* __restrict__ denom,
                                                   float* __restrict__ out) {
    long long idx = (long long)blockIdx.x * 256 + threadIdx.x;
    if (idx >= (long long)N_EDGES * HD) return;
    int e = (int)(idx >> 6);
    int c = (int)(idx & 63);
    int h = c >> 4;
    int s = src[e], d = dst[e];
    int dh = d * HEADS + h;
    float x = leaky(el[s * HEADS + h] + er[dh]);
    float alpha = __expf(x - emax[dh]) / denom[dh];
    atomicAdd(&out[d * HD + c], hws[s * HD + c] * alpha);
}

// ---------------------------------------------------------------------------
// Launch
// ---------------------------------------------------------------------------
extern "C" void kernel_launch(void* const* d_in, const int* in_sizes, int n_in,
                              void* d_out, int out_size, void* d_ws, size_t ws_size,
                              hipStream_t stream) {
    const float* feat   = (const float*)d_in[0];
    const float* W      = (const float*)d_in[1];
    const float* attn_l = (const float*)d_in[2];
    const float* attn_r = (const float*)d_in[3];
    const float* bias   = (const float*)d_in[4];
    const int*   src    = (const int*)d_in[5];
    const int*   dst    = (const int*)d_in[6];
    float* out = (float*)d_out;

    // Workspace layout (fp32): h [N*64] | el [N*4] | er [N*4] | emax [N*4] | denom [N*4]
    float* hws   = (float*)d_ws;
    float* el    = hws + (size_t)N_NODES * HD;
    float* er    = el + (size_t)N_NODES * HEADS;
    float* emax  = er + (size_t)N_NODES * HEADS;
    float* denom = emax + (size_t)N_NODES * HEADS;

    // 1) projection
    k_gemm<<<(N_NODES + 63) / 64, 256, 0, stream>>>(feat, W, hws);
    // 2) attention halves
    k_attn_halves<<<(N_NODES * HEADS + 255) / 256, 256, 0, stream>>>(hws, attn_l, attn_r, el, er);
    // 3) init out/emax/denom
    k_init<<<(N_NODES * HD + 255) / 256, 256, 0, stream>>>(out, bias, emax, denom);
    // 4) segment max
    k_edge_max<<<(N_EDGES * HEADS + 255) / 256, 256, 0, stream>>>(src, dst, el, er, emax);
    // 5) segment expsum
    k_edge_expsum<<<(N_EDGES * HEADS + 255) / 256, 256, 0, stream>>>(src, dst, el, er, emax, denom);
    // 6) weighted aggregation
    long long total = (long long)N_EDGES * HD;
    k_aggregate<<<(int)((total + 255) / 256), 256, 0, stream>>>(src, dst, hws, el, er, emax, denom, out);
}

// Round 2
// 687.999 us; speedup vs baseline: 1.0681x; 1.0681x over previous
//
#include <hip/hip_runtime.h>
#include <math.h>

#define N_NODES 100000
#define N_EDGES 1600000
#define IN_DIM  128
#define HD      64     // HEADS * OUT_DIM
#define HEADS   4
#define ODIM    16
#define NEG_SLOPE 0.2f

// ---------------------------------------------------------------------------
// Kernel 1: h = feat @ W   (N x 128) @ (128 x 64) -> (N x 64)
// ---------------------------------------------------------------------------
__global__ __launch_bounds__(256) void k_gemm(const float* __restrict__ feat,
                                              const float* __restrict__ W,
                                              float* __restrict__ hws) {
    __shared__ float sF[64][IN_DIM + 1];
    __shared__ float sW[IN_DIM][HD];

    const int tid  = threadIdx.x;
    const int base = blockIdx.x * 64;

    for (int i = tid; i < IN_DIM * HD; i += 256) {
        sW[i >> 6][i & 63] = W[i];
    }
    for (int i = tid; i < 64 * IN_DIM; i += 256) {
        int n = i >> 7, k = i & 127;
        int gn = base + n;
        sF[n][k] = (gn < N_NODES) ? feat[gn * IN_DIM + k] : 0.f;
    }
    __syncthreads();

    const int cg = (tid & 15) * 4;
    const int rg = (tid >> 4) * 4;

    float acc[4][4] = {};
    for (int k = 0; k < IN_DIM; ++k) {
        float4 wv = *(const float4*)&sW[k][cg];
        float f0 = sF[rg + 0][k];
        float f1 = sF[rg + 1][k];
        float f2 = sF[rg + 2][k];
        float f3 = sF[rg + 3][k];
        acc[0][0] += f0 * wv.x; acc[0][1] += f0 * wv.y; acc[0][2] += f0 * wv.z; acc[0][3] += f0 * wv.w;
        acc[1][0] += f1 * wv.x; acc[1][1] += f1 * wv.y; acc[1][2] += f1 * wv.z; acc[1][3] += f1 * wv.w;
        acc[2][0] += f2 * wv.x; acc[2][1] += f2 * wv.y; acc[2][2] += f2 * wv.z; acc[2][3] += f2 * wv.w;
        acc[3][0] += f3 * wv.x; acc[3][1] += f3 * wv.y; acc[3][2] += f3 * wv.z; acc[3][3] += f3 * wv.w;
    }

    for (int r = 0; r < 4; ++r) {
        int gn = base + rg + r;
        if (gn < N_NODES) {
            float4 v = make_float4(acc[r][0], acc[r][1], acc[r][2], acc[r][3]);
            *(float4*)&hws[gn * HD + cg] = v;
        }
    }
}

// ---------------------------------------------------------------------------
// Kernel 2: per-node attention halves el/er  [N, H]
// ---------------------------------------------------------------------------
__global__ __launch_bounds__(256) void k_attn_halves(const float* __restrict__ hws,
                                                     const float* __restrict__ attn_l,
                                                     const float* __restrict__ attn_r,
                                                     float* __restrict__ el,
                                                     float* __restrict__ er) {
    int idx = blockIdx.x * 256 + threadIdx.x;
    if (idx >= N_NODES * HEADS) return;
    int n = idx >> 2, h = idx & 3;
    const float* hp = hws + n * HD + h * ODIM;
    const float* al = attn_l + h * ODIM;
    const float* ar = attn_r + h * ODIM;
    float sl = 0.f, sr = 0.f;
    #pragma unroll
    for (int d = 0; d < ODIM; ++d) {
        float v = hp[d];
        sl += v * al[d];
        sr += v * ar[d];
    }
    el[idx] = sl;
    er[idx] = sr;
}

// ---------------------------------------------------------------------------
// Kernel 3: degree histogram (deg zeroed via hipMemsetAsync beforehand)
// ---------------------------------------------------------------------------
__global__ __launch_bounds__(256) void k_hist(const int* __restrict__ dst,
                                              int* __restrict__ deg) {
    int e = blockIdx.x * 256 + threadIdx.x;
    if (e < N_EDGES) atomicAdd(&deg[dst[e]], 1);
}

// ---------------------------------------------------------------------------
// Kernel 4: single-block exclusive scan of deg -> cursor (initial offsets)
// 1024 threads, each handles a contiguous chunk; LDS Hillis-Steele across
// thread sums.
// ---------------------------------------------------------------------------
__global__ __launch_bounds__(1024) void k_scan(const int* __restrict__ deg,
                                               int* __restrict__ cursor) {
    __shared__ int sums[1024];
    const int t = threadIdx.x;
    const int CH = (N_NODES + 1023) / 1024;  // 98
    int beg = t * CH;
    int end = beg + CH; if (end > N_NODES) end = N_NODES;
    int s = 0;
    for (int i = beg; i < end; ++i) s += deg[i];
    sums[t] = s;
    __syncthreads();
    for (int off = 1; off < 1024; off <<= 1) {
        int v = (t >= off) ? sums[t - off] : 0;
        __syncthreads();
        sums[t] += v;
        __syncthreads();
    }
    int run = (t == 0) ? 0 : sums[t - 1];
    for (int i = beg; i < end; ++i) {
        cursor[i] = run;
        run += deg[i];
    }
}

// ---------------------------------------------------------------------------
// Kernel 5: scatter edges into dst-sorted order. cursor ends as segment END.
// ---------------------------------------------------------------------------
__global__ __launch_bounds__(256) void k_scatter(const int* __restrict__ src,
                                                 const int* __restrict__ dst,
                                                 int* __restrict__ cursor,
                                                 int* __restrict__ sorted_src) {
    int e = blockIdx.x * 256 + threadIdx.x;
    if (e >= N_EDGES) return;
    int d = dst[e];
    int pos = atomicAdd(&cursor[d], 1);
    sorted_src[pos] = src[e];
}

// ---------------------------------------------------------------------------
// Kernel 6: per-node softmax + aggregation. One wave (64 lanes) per node.
// Lane c handles output column c (head = c>>4). Pass 1: online softmax stats
// per (head, slot) lane, butterfly-merged over the 16 lanes of each head.
// Pass 2: register accumulation of alpha * h[src], single store per element.
// ---------------------------------------------------------------------------
__global__ __launch_bounds__(256) void k_aggregate_csr(const int* __restrict__ sorted_src,
                                                       const int* __restrict__ cursor_end,
                                                       const int* __restrict__ deg,
                                                       const float* __restrict__ hws,
                                                       const float* __restrict__ el,
                                                       const float* __restrict__ er,
                                                       const float* __restrict__ bias,
                                                       float* __restrict__ out) {
    const int wave = threadIdx.x >> 6;
    const int lane = threadIdx.x & 63;
    const int node = blockIdx.x * 4 + wave;
    if (node >= N_NODES) return;

    const int end   = cursor_end[node];
    const int dn    = deg[node];
    const int start = end - dn;

    // ---- pass 1: softmax stats. lane = slot*4 + head ----
    const int h1   = lane & 3;
    const int slot = lane >> 2;
    const float er1 = er[node * HEADS + h1];
    float m = -1e30f, lsum = 0.f;
    for (int j = start + slot; j < end; j += 16) {
        int s = sorted_src[j];
        float x = el[s * HEADS + h1] + er1;
        x = x > 0.f ? x : NEG_SLOPE * x;
        if (x > m) { lsum *= __expf(m - x); m = x; }
        lsum += __expf(x - m);
    }
    // merge across the 16 lanes sharing a head (lane xor 4,8,16,32 keeps head)
    #pragma unroll
    for (int o = 4; o < 64; o <<= 1) {
        float m2 = __shfl_xor(m, o);
        float l2 = __shfl_xor(lsum, o);
        float M  = fmaxf(m, m2);
        lsum = lsum * __expf(m - M) + l2 * __expf(m2 - M);
        m = M;
    }
    // broadcast this column's head stats: lane (c>>4) holds head (c>>4)
    const int hc = lane >> 4;
    const float mh    = __shfl(m, hc);
    const float lh    = __shfl(lsum, hc);
    const float inv_l = (dn > 0) ? 1.f / lh : 0.f;
    const float erc   = er[node * HEADS + hc];

    // ---- pass 2: weighted aggregation ----
    float acc = 0.f;
    for (int j = start; j < end; ++j) {
        int s = sorted_src[j];
        float x = el[s * HEADS + hc] + erc;
        x = x > 0.f ? x : NEG_SLOPE * x;
        float alpha = __expf(x - mh) * inv_l;
        acc = fmaf(alpha, hws[s * HD + lane], acc);
    }
    out[node * HD + lane] = acc + bias[lane];
}

// ---------------------------------------------------------------------------
// Launch
// ---------------------------------------------------------------------------
extern "C" void kernel_launch(void* const* d_in, const int* in_sizes, int n_in,
                              void* d_out, int out_size, void* d_ws, size_t ws_size,
                              hipStream_t stream) {
    const float* feat   = (const float*)d_in[0];
    const float* W      = (const float*)d_in[1];
    const float* attn_l = (const float*)d_in[2];
    const float* attn_r = (const float*)d_in[3];
    const float* bias   = (const float*)d_in[4];
    const int*   src    = (const int*)d_in[5];
    const int*   dst    = (const int*)d_in[6];
    float* out = (float*)d_out;

    // Workspace layout:
    // h [N*64 f32] | el [N*4] | er [N*4] | deg [N i32] | cursor [N i32] | sorted_src [E i32]
    float* hws   = (float*)d_ws;
    float* el    = hws + (size_t)N_NODES * HD;
    float* er    = el + (size_t)N_NODES * HEADS;
    int*   deg        = (int*)(er + (size_t)N_NODES * HEADS);
    int*   cursor     = deg + N_NODES;
    int*   sorted_src = cursor + N_NODES;

    // 1) projection
    k_gemm<<<(N_NODES + 63) / 64, 256, 0, stream>>>(feat, W, hws);
    // 2) attention halves
    k_attn_halves<<<(N_NODES * HEADS + 255) / 256, 256, 0, stream>>>(hws, attn_l, attn_r, el, er);
    // 3) CSR build: zero histogram, count, scan, scatter
    hipMemsetAsync(deg, 0, N_NODES * sizeof(int), stream);
    k_hist<<<(N_EDGES + 255) / 256, 256, 0, stream>>>(dst, deg);
    k_scan<<<1, 1024, 0, stream>>>(deg, cursor);
    k_scatter<<<(N_EDGES + 255) / 256, 256, 0, stream>>>(src, dst, cursor, sorted_src);
    // 4) fused softmax + aggregation, one wave per node
    k_aggregate_csr<<<(N_NODES + 3) / 4, 256, 0, stream>>>(sorted_src, cursor, deg, hws, el, er, bias, out);
}

// Round 3
// 480.764 us; speedup vs baseline: 1.5285x; 1.4311x over previous
//
#include <hip/hip_runtime.h>
#include <math.h>

#define N_NODES 100000
#define N_EDGES 1600000
#define IN_DIM  128
#define HD      64     // HEADS * OUT_DIM
#define HEADS   4
#define ODIM    16
#define NEG_SLOPE 0.2f

#define SCAN_BLOCKS ((N_NODES + 255) / 256)   // 391

// ---------------------------------------------------------------------------
// Kernel 1: h = feat @ W  + fused el/er epilogue.
// 64x64 tile, 256 threads, 4x4 register tile, k-unrolled by 4, all-float4 LDS.
// el[n][h] = dot(h[n][h*16:...], attn_l[h]); acc tile already holds h values,
// reduce partial dots across the 4 lanes sharing a (node,head).
// ---------------------------------------------------------------------------
__global__ __launch_bounds__(256) void k_gemm_fused(const float* __restrict__ feat,
                                                    const float* __restrict__ W,
                                                    const float* __restrict__ attn_l,
                                                    const float* __restrict__ attn_r,
                                                    float* __restrict__ hws,
                                                    float* __restrict__ el,
                                                    float* __restrict__ er) {
    __shared__ float sF[64][IN_DIM];   // broadcast reads -> no padding needed
    __shared__ float sW[IN_DIM][HD];

    const int tid  = threadIdx.x;
    const int base = blockIdx.x * 64;

    for (int i = tid; i < IN_DIM * HD; i += 256) sW[i >> 6][i & 63] = W[i];
    for (int i = tid; i < 64 * IN_DIM; i += 256) {
        int n = i >> 7, k = i & 127;
        int gn = base + n;
        sF[n][k] = (gn < N_NODES) ? feat[gn * IN_DIM + k] : 0.f;
    }
    __syncthreads();

    const int cg = (tid & 15) * 4;   // col base
    const int rg = (tid >> 4) * 4;   // local node base

    float acc[4][4] = {};
    for (int k = 0; k < IN_DIM; k += 4) {
        float4 w0 = *(const float4*)&sW[k + 0][cg];
        float4 w1 = *(const float4*)&sW[k + 1][cg];
        float4 w2 = *(const float4*)&sW[k + 2][cg];
        float4 w3 = *(const float4*)&sW[k + 3][cg];
        #pragma unroll
        for (int r = 0; r < 4; ++r) {
            float4 f = *(const float4*)&sF[rg + r][k];
            acc[r][0] += f.x * w0.x + f.y * w1.x + f.z * w2.x + f.w * w3.x;
            acc[r][1] += f.x * w0.y + f.y * w1.y + f.z * w2.y + f.w * w3.y;
            acc[r][2] += f.x * w0.z + f.y * w1.z + f.z * w2.z + f.w * w3.z;
            acc[r][3] += f.x * w0.w + f.y * w1.w + f.z * w2.w + f.w * w3.w;
        }
    }

    #pragma unroll
    for (int r = 0; r < 4; ++r) {
        int gn = base + rg + r;
        if (gn < N_NODES) {
            *(float4*)&hws[gn * HD + cg] =
                make_float4(acc[r][0], acc[r][1], acc[r][2], acc[r][3]);
        }
    }

    // fused el/er: attn vectors are flat [H*16] = [64]; cg indexes directly
    float4 al = *(const float4*)&attn_l[cg];
    float4 ar = *(const float4*)&attn_r[cg];
    const int head = (tid & 15) >> 2;
    #pragma unroll
    for (int r = 0; r < 4; ++r) {
        float pl = acc[r][0]*al.x + acc[r][1]*al.y + acc[r][2]*al.z + acc[r][3]*al.w;
        float pr = acc[r][0]*ar.x + acc[r][1]*ar.y + acc[r][2]*ar.z + acc[r][3]*ar.w;
        pl += __shfl_xor(pl, 1); pl += __shfl_xor(pl, 2);
        pr += __shfl_xor(pr, 1); pr += __shfl_xor(pr, 2);
        int gn = base + rg + r;
        if ((tid & 3) == 0 && gn < N_NODES) {
            el[gn * HEADS + head] = pl;
            er[gn * HEADS + head] = pr;
        }
    }
}

// ---------------------------------------------------------------------------
// CSR build: histogram -> 3-kernel parallel exclusive scan -> scatter
// ---------------------------------------------------------------------------
__global__ __launch_bounds__(256) void k_hist(const int* __restrict__ dst,
                                              int* __restrict__ deg) {
    int e = blockIdx.x * 256 + threadIdx.x;
    if (e < N_EDGES) atomicAdd(&deg[dst[e]], 1);
}

__global__ __launch_bounds__(256) void k_scan1(const int* __restrict__ deg,
                                               int* __restrict__ cursor,
                                               int* __restrict__ partials) {
    const int tid  = threadIdx.x;
    const int i    = blockIdx.x * 256 + tid;
    const int lane = tid & 63, wave = tid >> 6;
    int v = (i < N_NODES) ? deg[i] : 0;
    int x = v;
    #pragma unroll
    for (int o = 1; o < 64; o <<= 1) {
        int t = __shfl_up(x, o);
        if (lane >= o) x += t;
    }
    __shared__ int wsum[4];
    if (lane == 63) wsum[wave] = x;
    __syncthreads();
    if (tid == 0) {
        int r = 0;
        #pragma unroll
        for (int w = 0; w < 4; ++w) { int t = wsum[w]; wsum[w] = r; r += t; }
    }
    __syncthreads();
    int excl = x - v + wsum[wave];
    if (i < N_NODES) cursor[i] = excl;
    if (tid == 255) partials[blockIdx.x] = excl + v;
}

__global__ __launch_bounds__(512) void k_scan2(int* __restrict__ partials) {
    __shared__ int s[512];
    const int t = threadIdx.x;
    int v = (t < SCAN_BLOCKS) ? partials[t] : 0;
    s[t] = v;
    __syncthreads();
    for (int o = 1; o < 512; o <<= 1) {
        int tv = (t >= o) ? s[t - o] : 0;
        __syncthreads();
        s[t] += tv;
        __syncthreads();
    }
    if (t < SCAN_BLOCKS) partials[t] = s[t] - v;   // exclusive
}

__global__ __launch_bounds__(256) void k_scan3(int* __restrict__ cursor,
                                               const int* __restrict__ partials) {
    int i = blockIdx.x * 256 + threadIdx.x;
    if (i < N_NODES) cursor[i] += partials[blockIdx.x];
}

__global__ __launch_bounds__(256) void k_scatter(const int* __restrict__ src,
                                                 const int* __restrict__ dst,
                                                 int* __restrict__ cursor,
                                                 int* __restrict__ sorted_src) {
    int e = blockIdx.x * 256 + threadIdx.x;
    if (e >= N_EDGES) return;
    int pos = atomicAdd(&cursor[dst[e]], 1);
    sorted_src[pos] = src[e];
}

// ---------------------------------------------------------------------------
// Kernel: flash-style single-pass softmax+aggregate. One wave per node.
// Chunk of 16 edges: producer lanes (slot=lane>>2, h1=lane&3) compute logits
// in parallel, chunk max/sum via xor-shuffles, online rescale of the
// consumer accumulator (lane = output col, head hc=lane>>4), then 16
// independent hws row-gathers per chunk (high MLP).
// ---------------------------------------------------------------------------
__global__ __launch_bounds__(256) void k_aggregate_csr(
        const int* __restrict__ sorted_src,
        const int* __restrict__ cursor_end,
        const int* __restrict__ deg,
        const float* __restrict__ hws,
        const float* __restrict__ el,
        const float* __restrict__ er,
        const float* __restrict__ bias,
        float* __restrict__ out) {
    const int wave = threadIdx.x >> 6;
    const int lane = threadIdx.x & 63;
    const int node = blockIdx.x * 4 + wave;
    if (node >= N_NODES) return;

    const int end   = cursor_end[node];
    const int dn    = deg[node];
    const int start = end - dn;

    const int h1   = lane & 3;     // producer head
    const int slot = lane >> 2;    // producer edge slot (0..15)
    const int hc   = lane >> 4;    // consumer head (lane = output col)
    const float er1 = er[node * HEADS + h1];

    float m_p = -1e30f, l_p = 0.f;  // producer softmax state (head h1)
    float m_c = -1e30f;             // consumer tracked max (head hc)
    float acc = 0.f;

    for (int j0 = start; j0 < end; j0 += 16) {
        int j = j0 + slot;
        int s = 0;
        float x = -1e30f;
        if (j < end) {
            s = sorted_src[j];
            float t = el[s * HEADS + h1] + er1;
            x = t > 0.f ? t : NEG_SLOPE * t;
        }
        // chunk max per head (reduce over slot bits 4,8,16,32)
        float cm = x;
        cm = fmaxf(cm, __shfl_xor(cm, 4));
        cm = fmaxf(cm, __shfl_xor(cm, 8));
        cm = fmaxf(cm, __shfl_xor(cm, 16));
        cm = fmaxf(cm, __shfl_xor(cm, 32));
        float newm = fmaxf(m_p, cm);
        float p = __expf(x - newm);          // invalid lanes -> exp(-huge)=0
        float cs = p;
        cs += __shfl_xor(cs, 4);
        cs += __shfl_xor(cs, 8);
        cs += __shfl_xor(cs, 16);
        cs += __shfl_xor(cs, 32);
        l_p = l_p * __expf(m_p - newm) + cs;
        m_p = newm;

        // consumer: rescale acc to new max of its head
        float mc_new = __shfl(m_p, hc);      // lane hc holds head-hc state
        acc *= __expf(m_c - mc_new);
        m_c = mc_new;

        int cnt = end - j0; if (cnt > 16) cnt = 16;
        for (int e = 0; e < cnt; ++e) {
            float pe = __shfl(p, e * 4 + hc);
            int   se = __shfl(s, e * 4);
            acc = fmaf(pe, hws[se * HD + lane], acc);
        }
    }

    float l   = __shfl(l_p, hc);
    float inv = (l > 0.f) ? 1.f / l : 0.f;
    out[node * HD + lane] = acc * inv + bias[lane];
}

// ---------------------------------------------------------------------------
// Launch
// ---------------------------------------------------------------------------
extern "C" void kernel_launch(void* const* d_in, const int* in_sizes, int n_in,
                              void* d_out, int out_size, void* d_ws, size_t ws_size,
                              hipStream_t stream) {
    const float* feat   = (const float*)d_in[0];
    const float* W      = (const float*)d_in[1];
    const float* attn_l = (const float*)d_in[2];
    const float* attn_r = (const float*)d_in[3];
    const float* bias   = (const float*)d_in[4];
    const int*   src    = (const int*)d_in[5];
    const int*   dst    = (const int*)d_in[6];
    float* out = (float*)d_out;

    // ws: h [N*64 f32] | el [N*4] | er [N*4] | deg [N] | cursor [N] |
    //     sorted_src [E] | partials [SCAN_BLOCKS]
    float* hws   = (float*)d_ws;
    float* el    = hws + (size_t)N_NODES * HD;
    float* er    = el + (size_t)N_NODES * HEADS;
    int*   deg        = (int*)(er + (size_t)N_NODES * HEADS);
    int*   cursor     = deg + N_NODES;
    int*   sorted_src = cursor + N_NODES;
    int*   partials   = sorted_src + N_EDGES;

    // 1) projection + fused el/er
    k_gemm_fused<<<(N_NODES + 63) / 64, 256, 0, stream>>>(feat, W, attn_l, attn_r,
                                                          hws, el, er);
    // 2) CSR build (independent of gemm)
    hipMemsetAsync(deg, 0, N_NODES * sizeof(int), stream);
    k_hist<<<(N_EDGES + 255) / 256, 256, 0, stream>>>(dst, deg);
    k_scan1<<<SCAN_BLOCKS, 256, 0, stream>>>(deg, cursor, partials);
    k_scan2<<<1, 512, 0, stream>>>(partials);
    k_scan3<<<SCAN_BLOCKS, 256, 0, stream>>>(cursor, partials);
    k_scatter<<<(N_EDGES + 255) / 256, 256, 0, stream>>>(src, dst, cursor, sorted_src);
    // 3) fused softmax + aggregation, one wave per node
    k_aggregate_csr<<<(N_NODES + 3) / 4, 256, 0, stream>>>(sorted_src, cursor, deg,
                                                           hws, el, er, bias, out);
}